// Round 14
// baseline (1260.795 us; speedup 1.0000x reference)
//
#include <hip/hip_runtime.h>
#include <hip/hip_cooperative_groups.h>

namespace cg = cooperative_groups;

#define NSUB 262144
#define NG   8192
#define DIM  128
#define NT   10

typedef __attribute__((ext_vector_type(4))) float f32x4;
typedef __attribute__((ext_vector_type(8))) short short8;
typedef unsigned short ushort_t;
typedef unsigned int uint_t;

__device__ __forceinline__ float bf2f(ushort_t u){
    union { uint_t i; float f; } v; v.i = ((uint_t)u) << 16; return v.f;
}
__device__ __forceinline__ ushort_t f2bf(float f){
    union { __bf16 b; ushort_t u; } v; v.b = (__bf16)f; return v.u;
}

// ---------------------------------------------------------------------------
// Frag layouts (verified R2/R3):  A (Wt): 16B chunk = ((i*4+ks)*8+f)*64+lane.
// B: lane ln holds rows {q*16+(ln&15)} cols ks*32+(ln>>4)*8..+8.
// seg LDS tile: [128 rows][272 B] (16B-mult stride; 2-way banks on all paths).
// R14: cooperative mega-kernel — h stays on chip (regs+LDS) across all 3
// layers; h0 read once; hbuf eliminated. Fallback = R13 chain if coop fails.
// ---------------------------------------------------------------------------

__global__ __launch_bounds__(256) void wprep_kernel(const float* __restrict__ Wfc,
                                                    ushort_t* __restrict__ Wt)
{
    int t = blockIdx.x * 256 + threadIdx.x;        // 0..6143
    int i   = t >> 11;
    int rem = t & 2047;
    int ks  = rem >> 9;
    int f   = (rem >> 6) & 7;
    int l   = rem & 63;
    int c   = f * 16 + (l & 15);
    int kb  = ks * 32 + (l >> 4) * 8;
    short8 v;
    #pragma unroll
    for (int j = 0; j < 8; j++)
        v[j] = (short)f2bf(Wfc[i * 16384 + (kb + j) * 128 + c]);
    *(short8*)(Wt + (long)t * 8) = v;
}

// ======================= device helpers (mega kernel) =======================

__device__ __forceinline__ void seg_global(const float* __restrict__ h0, long t,
                                           const int* sidxp, float* gsum,
                                           float* cnt, int tid)
{
    const int cg_ = tid & 31, ch = tid >> 5;
    const int r0 = ch * 16;
    const long base = t * 128;
    f32x4 v[16];
    #pragma unroll
    for (int j = 0; j < 16; j++)
        v[j] = *(const f32x4*)(h0 + (base + r0 + j) * 128 + cg_ * 4);
    f32x4 acc = {0.f, 0.f, 0.f, 0.f};
    int cur = sidxp[r0], n = 0;
    #pragma unroll
    for (int j = 0; j < 16; j++){
        const int g = sidxp[r0 + j];
        if (g != cur){
            float* gp = gsum + (long)cur * 128 + cg_ * 4;
            atomicAdd(gp + 0, acc[0]); atomicAdd(gp + 1, acc[1]);
            atomicAdd(gp + 2, acc[2]); atomicAdd(gp + 3, acc[3]);
            if (cg_ == 0) atomicAdd(cnt + cur, (float)n);
            acc = {0.f, 0.f, 0.f, 0.f}; n = 0; cur = g;
        }
        acc += v[j]; n++;
    }
    float* gp = gsum + (long)cur * 128 + cg_ * 4;
    atomicAdd(gp + 0, acc[0]); atomicAdd(gp + 1, acc[1]);
    atomicAdd(gp + 2, acc[2]); atomicAdd(gp + 3, acc[3]);
    if (cg_ == 0) atomicAdd(cnt + cur, (float)n);
}

__device__ __forceinline__ void fill_b8(const float* __restrict__ h0, long t,
                                        short8* b8, int tid)
{
    const int ln = tid & 63;
    const int ln15 = ln & 15, grp = ln >> 4;
    const int wv = tid >> 6;
    #pragma unroll
    for (int ks = 0; ks < 4; ks++)
        #pragma unroll
        for (int q = 0; q < 2; q++){
            const long r = t * 128 + wv * 32 + q * 16 + ln15;
            const float* p = h0 + r * 128 + ks * 32 + grp * 8;
            f32x4 v0 = *(const f32x4*)p;
            f32x4 v1 = *(const f32x4*)(p + 4);
            short8 s;
            #pragma unroll
            for (int j = 0; j < 4; j++){
                s[j]     = (short)f2bf(v0[j]);
                s[4 + j] = (short)f2bf(v1[j]);
            }
            b8[ks * 2 + q] = s;
        }
}

__device__ __forceinline__ void x2_phase(char* buf, float* g, const float* cnt,
                                         const float* __restrict__ Wsum,
                                         const float* __restrict__ bsum,
                                         const float* __restrict__ bfc,
                                         float* __restrict__ x2b, int bid0, int tid)
{
    float* gm   = (float*)buf;              // [16][128]
    float* invc = (float*)(buf + 8192);     // [16]
    const int r0 = bid0 * 16;
    if (tid < 16) invc[tid] = 1.f / fmaxf(cnt[r0 + tid], 1.f);
    __syncthreads();
    #pragma unroll
    for (int p = 0; p < 8; p++){
        int e = tid + p * 256;
        int row = e >> 7, col = e & 127;
        float val = g[(long)(r0 + row) * 128 + col];
        gm[row * 128 + col] = val * invc[row];
        g[(long)(r0 + row) * 128 + col] = 0.f;      // re-zero for ping-pong
    }
    __syncthreads();
    const int c = tid & 127, rh = tid >> 7;
    float acc[8];
    #pragma unroll
    for (int i = 0; i < 8; i++) acc[i] = bsum[c] + bfc[c];
    for (int k = 0; k < 128; k++){
        float w = Wsum[k * 128 + c];
        #pragma unroll
        for (int i = 0; i < 8; i++) acc[i] += gm[(rh * 8 + i) * 128 + k] * w;
    }
    #pragma unroll
    for (int i = 0; i < 8; i++) x2b[(long)(r0 + rh * 8 + i) * 128 + c] = acc[i];
}

template<bool EXTRACT>
__device__ __forceinline__ void layer_phase(short8* b8, ushort_t* segb,
                                            const int* sidxp,
                                            const ushort_t* __restrict__ Wt,
                                            const float* __restrict__ x2b,
                                            float* __restrict__ gnext, int tid)
{
    const int ln = tid & 63, wv = tid >> 6;
    const int ln15 = ln & 15, grp = ln >> 4;

    // GEMM + epilogue in two 4-column-group halves (acc stays at 32 VGPR)
    #pragma unroll
    for (int half = 0; half < 2; half++){
        f32x4 acc[2][4];
        #pragma unroll
        for (int q = 0; q < 2; q++)
            #pragma unroll
            for (int f = 0; f < 4; f++) acc[q][f] = {0.f, 0.f, 0.f, 0.f};
        #pragma unroll
        for (int ks = 0; ks < 4; ks++){
            short8 a[4];
            #pragma unroll
            for (int f = 0; f < 4; f++)
                a[f] = *(const short8*)(Wt + ((long)(ks * 8 + half * 4 + f) * 64 + ln) * 8);
            #pragma unroll
            for (int f = 0; f < 4; f++)
                #pragma unroll
                for (int q = 0; q < 2; q++)
                    acc[q][f] = __builtin_amdgcn_mfma_f32_16x16x32_bf16(a[f], b8[ks * 2 + q], acc[q][f], 0, 0, 0);
        }
        #pragma unroll
        for (int q = 0; q < 2; q++){
            const int lr = wv * 32 + q * 16 + ln15;      // local row 0..127
            const int gg = sidxp[lr];
            const float* x2r = x2b + (long)gg * 128;
            #pragma unroll
            for (int f2 = 0; f2 < 4; f2++){
                const int f = half * 4 + f2;
                const int cb = f * 16 + grp * 4;
                f32x4 xv = *(const f32x4*)(x2r + cb);
                ushort_t h4[4];
                #pragma unroll
                for (int i = 0; i < 4; i++){
                    float v = acc[q][f2][i] + xv[i];
                    v = v > 0.f ? v : (__expf(v) - 1.f);
                    h4[i] = f2bf(v);
                }
                uint2 pk;
                pk.x = (uint_t)h4[0] | ((uint_t)h4[1] << 16);
                pk.y = (uint_t)h4[2] | ((uint_t)h4[3] << 16);
                *(uint2*)((char*)segb + lr * 272 + cb * 2) = pk;
            }
        }
    }

    // extract next layer's B-frags (own-wave rows only; ds ordering via waitcnt)
    if (EXTRACT){
        #pragma unroll
        for (int ks = 0; ks < 4; ks++)
            #pragma unroll
            for (int q = 0; q < 2; q++){
                const int lr = wv * 32 + q * 16 + ln15;
                b8[ks * 2 + q] = *(const short8*)((const char*)segb + lr * 272 + ks * 64 + grp * 16);
            }
    }
    __syncthreads();

    // fused segment-sum of this tile's output rows -> gnext
    const int c = tid & 63, ch2 = tid >> 6;
    const int rr0 = ch2 * 32;
    float a0 = 0.f, a1 = 0.f;
    int cur = sidxp[rr0];
    for (int j = 0; j < 32; j++){
        const int rr = rr0 + j;
        const int g = sidxp[rr];
        if (g != cur){
            atomicAdd(gnext + (long)cur * 128 + 2 * c,     a0);
            atomicAdd(gnext + (long)cur * 128 + 2 * c + 1, a1);
            a0 = a1 = 0.f; cur = g;
        }
        uint_t u = *(const uint_t*)((const char*)segb + rr * 272 + c * 4);
        a0 += bf2f((ushort_t)(u & 0xffff));
        a1 += bf2f((ushort_t)(u >> 16));
    }
    atomicAdd(gnext + (long)cur * 128 + 2 * c,     a0);
    atomicAdd(gnext + (long)cur * 128 + 2 * c + 1, a1);
    __syncthreads();                                    // segb reuse guard
}

__device__ __forceinline__ void head_phase(char* buf, const float* __restrict__ g,
                                           const float* __restrict__ cnt,
                                           const float* __restrict__ Wf1,
                                           const float* __restrict__ bf1,
                                           const float* __restrict__ Wf2,
                                           const float* __restrict__ bf2,
                                           float* __restrict__ out, int bid0, int tid)
{
    float* hm   = (float*)buf;               // [8][128]
    float* t1   = (float*)(buf + 4096);      // [8][256]
    float* invc = (float*)(buf + 12288);     // [8]
    const int r0 = bid0 * 8;
    if (tid < 8) invc[tid] = 1.f / fmaxf(cnt[r0 + tid], 1.f);
    __syncthreads();
    #pragma unroll
    for (int p = 0; p < 4; p++){
        int e = tid + p * 256;
        int row = e >> 7, col = e & 127;
        hm[row * 128 + col] = g[(long)(r0 + row) * 128 + col] * invc[row];
    }
    __syncthreads();
    {
        const int c = tid;
        float acc[8];
        #pragma unroll
        for (int r = 0; r < 8; r++) acc[r] = bf1[c];
        for (int k = 0; k < 128; k++){
            float w = Wf1[k * 256 + c];
            #pragma unroll
            for (int r = 0; r < 8; r++) acc[r] += hm[r * 128 + k] * w;
        }
        #pragma unroll
        for (int r = 0; r < 8; r++) t1[r * 256 + c] = fmaxf(acc[r], 0.f);
    }
    __syncthreads();
    if (tid < 80){
        const int r = tid / 10, c = tid % 10;
        float acc = bf2[c];
        for (int k = 0; k < 256; k++) acc += t1[r * 256 + k] * Wf2[k * 10 + c];
        out[(long)(r0 + r) * 10 + c] = acc;
    }
}

// ============================ mega kernel ============================
__global__ __launch_bounds__(256, 4) void mega_kernel(
    const float* __restrict__ h0, const int* __restrict__ idx,
    const ushort_t* __restrict__ Wt,
    const float* __restrict__ Wsum, const float* __restrict__ bsum,
    const float* __restrict__ bfc,
    const float* __restrict__ Wf1, const float* __restrict__ bf1,
    const float* __restrict__ Wf2, const float* __restrict__ bf2,
    float* g0, float* g1, float* x2b, float* cnt, float* out)
{
    cg::grid_group grid = cg::this_grid();
    __shared__ __align__(16) char buf[35840];       // seg [128][272B] + sidx
    ushort_t* segb = (ushort_t*)buf;
    int* sidx = (int*)(buf + 34816);                // [256]
    const int tid = threadIdx.x;
    const int bid0 = blockIdx.x;                    // 0..1023
    const long tA = ((bid0 & 7) << 7) | (bid0 >> 3);  // XCD swizzle, bijective
    const long tB = tA + 1024;

    if (tid < 128) sidx[tid] = idx[tA * 128 + tid];
    else           sidx[tid] = idx[tB * 128 + (tid - 128)];
    __syncthreads();

    // P1: segsum+cnt of h0 (fp32, exact) and bf16 B-frag conversion (regs)
    short8 b8A[8], b8B[8];
    seg_global(h0, tA, sidx,       g0, cnt, tid);
    fill_b8(h0, tA, b8A, tid);
    seg_global(h0, tB, sidx + 128, g0, cnt, tid);
    fill_b8(h0, tB, b8B, tid);
    grid.sync();

    // P2: x2 for layer 0 (512 blocks), re-zeroes g0
    if (bid0 < 512) x2_phase(buf, g0, cnt, Wsum, bsum, bfc, x2b, bid0, tid);
    grid.sync();

    // P3: layer 0 -> g1
    layer_phase<true >(b8A, segb, sidx,       Wt, x2b, g1, tid);
    layer_phase<true >(b8B, segb, sidx + 128, Wt, x2b, g1, tid);
    grid.sync();

    // P4: x2 for layer 1, re-zeroes g1
    if (bid0 < 512) x2_phase(buf, g1, cnt, Wsum + 16384, bsum + 128, bfc + 128, x2b, bid0, tid);
    grid.sync();

    // P5: layer 1 -> g0
    layer_phase<true >(b8A, segb, sidx,       Wt + 16384, x2b, g0, tid);
    layer_phase<true >(b8B, segb, sidx + 128, Wt + 16384, x2b, g0, tid);
    grid.sync();

    // P6: x2 for layer 2, re-zeroes g0
    if (bid0 < 512) x2_phase(buf, g0, cnt, Wsum + 32768, bsum + 256, bfc + 256, x2b, bid0, tid);
    grid.sync();

    // P7: layer 2 -> g1 (no extraction)
    layer_phase<false>(b8A, segb, sidx,       Wt + 32768, x2b, g1, tid);
    layer_phase<false>(b8B, segb, sidx + 128, Wt + 32768, x2b, g1, tid);
    grid.sync();

    // P8: head (all 1024 blocks, 8 graphs each)
    head_phase(buf, g1, cnt, Wf1, bf1, Wf2, bf2, out, bid0, tid);
}

// ===================== fallback kernels (R13 chain) =====================

__global__ __launch_bounds__(256) void seg0_kernel(const float* __restrict__ h0,
                                                   const int* __restrict__ idx,
                                                   float* __restrict__ gsum,
                                                   float* __restrict__ cnt)
{
    __shared__ int sidx[128];
    const int tid = threadIdx.x;
    const int bid = ((blockIdx.x & 7) << 8) | (blockIdx.x >> 3);
    const long base = (long)bid * 128;
    if (tid < 128) sidx[tid] = idx[base + tid];
    __syncthreads();
    seg_global(h0, bid, sidx, gsum, cnt, tid);
}

__global__ __launch_bounds__(256) void x2_kernel(float* g,
                                                 const float* __restrict__ cnt,
                                                 const float* __restrict__ Wsum,
                                                 const float* __restrict__ bsum,
                                                 const float* __restrict__ bfc,
                                                 float* __restrict__ x2)
{
    __shared__ __align__(16) char buf[8320];
    x2_phase(buf, g, cnt, Wsum, bsum, bfc, x2, blockIdx.x, threadIdx.x);
}

template<int FIRST, int NOWRITE>
__global__ __launch_bounds__(256, 4) void layer_kernel(const void* __restrict__ hin_,
                                                    ushort_t* hout,
                                                    const ushort_t* __restrict__ Wt,
                                                    const float* __restrict__ x2,
                                                    const int* __restrict__ idx,
                                                    float* __restrict__ gnext)
{
    __shared__ __align__(16) char buf[35840];
    ushort_t* segb = (ushort_t*)buf;
    int* sidx = (int*)(buf + 34816);
    const int tid = threadIdx.x;
    const int bid = ((blockIdx.x & 7) << 8) | (blockIdx.x >> 3);
    const long base = (long)bid * 128;
    if (tid < 128) sidx[tid] = idx[base + tid];

    short8 b8[8];
    if (FIRST) fill_b8((const float*)hin_, bid, b8, tid);
    else {
        const ushort_t* hp = (const ushort_t*)hin_;
        const int ln = tid & 63, wv = tid >> 6;
        const long Rbase = (long)bid * 8 + wv * 2;
        #pragma unroll
        for (int ks = 0; ks < 4; ks++)
            #pragma unroll
            for (int q = 0; q < 2; q++)
                b8[ks * 2 + q] = *(const short8*)(hp + (((Rbase + q) * 4 + ks) * 64 + ln) * 8);
    }
    __syncthreads();
    layer_phase<false>(b8, segb, sidx, Wt, x2, gnext, tid);

    if (!NOWRITE){
        // seg -> hout contiguous frag stores (1KB/wave-op)
        const int r15 = tid & 15, g4 = (tid >> 4) & 3, ks = tid >> 6;
        uint4* dst = (uint4*)hout + (long)bid * 2048 + tid;
        const char* srcc = (const char*)segb + ks * 64 + g4 * 16;
        #pragma unroll
        for (int rg = 0; rg < 8; rg++){
            uint4 val = *(const uint4*)(srcc + (rg * 16 + r15) * 272);
            dst[rg * 256] = val;
        }
    }
}

__global__ __launch_bounds__(256) void head_kernel(const float* __restrict__ g,
                                                   const float* __restrict__ cnt,
                                                   const float* __restrict__ Wf1,
                                                   const float* __restrict__ bf1,
                                                   const float* __restrict__ Wf2,
                                                   const float* __restrict__ bf2,
                                                   float* __restrict__ out)
{
    __shared__ __align__(16) char buf[12352];
    head_phase(buf, g, cnt, Wf1, bf1, Wf2, bf2, out, blockIdx.x, threadIdx.x);
}

// ---------------------------------------------------------------------------
extern "C" void kernel_launch(void* const* d_in, const int* in_sizes, int n_in,
                              void* d_out, int out_size, void* d_ws, size_t ws_size,
                              hipStream_t stream)
{
    const float* h0   = (const float*)d_in[0];
    const int*   idx  = (const int*)d_in[1];
    const float* Wfc  = (const float*)d_in[2];
    const float* bfc  = (const float*)d_in[3];
    const float* Wsum = (const float*)d_in[4];
    const float* bsum = (const float*)d_in[5];
    const float* Wf1  = (const float*)d_in[6];
    const float* bf1  = (const float*)d_in[7];
    const float* Wf2  = (const float*)d_in[8];
    const float* bf2  = (const float*)d_in[9];
    float* out = (float*)d_out;

    char* ws = (char*)d_ws;
    ushort_t* hbuf = (ushort_t*)ws;                 // 64 MB (fallback only)
    float* g0  = (float*)(ws + 67108864);           // 4 MB
    float* g1  = (float*)(ws + 71303168);           // 4 MB (contiguous w/ g0)
    float* x2  = (float*)(ws + 75497472);           // 4 MB
    float* cnt = (float*)(ws + 79691776);           // 32 KB
    ushort_t* Wt = (ushort_t*)(ws + 79724544);      // 96 KB (frag layout)
    if (ws_size < 79822848ull) return;              // fail loudly (poisoned out)

    hipMemsetAsync(g0, 0, 2 * NG * DIM * 4, stream);
    hipMemsetAsync(cnt, 0, NG * 4, stream);
    wprep_kernel<<<24, 256, 0, stream>>>(Wfc, Wt);

    void* kargs[15] = {
        (void*)&h0, (void*)&idx, (void*)&Wt,
        (void*)&Wsum, (void*)&bsum, (void*)&bfc,
        (void*)&Wf1, (void*)&bf1, (void*)&Wf2, (void*)&bf2,
        (void*)&g0, (void*)&g1, (void*)&x2, (void*)&cnt, (void*)&out
    };
    hipError_t err = hipLaunchCooperativeKernel((const void*)mega_kernel,
                                                dim3(1024), dim3(256),
                                                kargs, 0u, stream);
    if (err != hipSuccess){
        // fallback: R13 multi-kernel chain (identical math)
        seg0_kernel<<<NSUB / 128, 256, 0, stream>>>(h0, idx, g0, cnt);
        x2_kernel<<<NG / 16, 256, 0, stream>>>(g0, cnt, Wsum, bsum, bfc, x2);
        layer_kernel<1, 0><<<NSUB / 128, 256, 0, stream>>>(h0, hbuf, Wt, x2, idx, g1);
        x2_kernel<<<NG / 16, 256, 0, stream>>>(g1, cnt, Wsum + 16384, bsum + 128, bfc + 128, x2);
        layer_kernel<0, 0><<<NSUB / 128, 256, 0, stream>>>(hbuf, hbuf, Wt + 16384, x2, idx, g0);
        x2_kernel<<<NG / 16, 256, 0, stream>>>(g0, cnt, Wsum + 32768, bsum + 256, bfc + 256, x2);
        layer_kernel<0, 1><<<NSUB / 128, 256, 0, stream>>>(hbuf, hbuf, Wt + 32768, x2, idx, g1);
        head_kernel<<<NG / 8, 256, 0, stream>>>(g1, cnt, Wf1, bf1, Wf2, bf2, out);
    }
}

// Round 15
// 232.429 us; speedup vs baseline: 5.4244x; 5.4244x over previous
//
#include <hip/hip_runtime.h>

#define NSUB 262144
#define NG   8192
#define DIM  128
#define NT   10

typedef __attribute__((ext_vector_type(4))) float f32x4;
typedef __attribute__((ext_vector_type(8))) short short8;
typedef unsigned short ushort_t;
typedef unsigned int uint_t;

__device__ __forceinline__ float bf2f(ushort_t u){
    union { uint_t i; float f; } v; v.i = ((uint_t)u) << 16; return v.f;
}
__device__ __forceinline__ ushort_t f2bf(float f){
    union { __bf16 b; ushort_t u; } v; v.b = (__bf16)f; return v.u;
}

// ---------------------------------------------------------------------------
// R15 = R9 (best measured, 239.6us) + NOWRITE on layer 2's dead hout stores.
// Fragment layouts (verified R2/R3):
//  A (Wt):  16B chunk = ((i*4+ks)*8 + f)*64 + lane
//  B (h):   h[row][k] at chunk (R*4 + (k>>5))*64 + ((k>>3)&3)*16 + (row&15),
//           byte (k&7)*2, R = row>>4. 128-row block = contiguous 32KB.
// XCD swizzle (T1, bijective: 2048%8==0).
// ---------------------------------------------------------------------------

// prep: blocks 0..2055 zero g0||g1 (8MB) + cnt; blocks 2056..2079 do W prep.
__global__ __launch_bounds__(256) void prep_kernel(const float* __restrict__ Wfc,
                                                   ushort_t* __restrict__ Wt,
                                                   float* __restrict__ g,
                                                   float* __restrict__ cnt)
{
    const int b = blockIdx.x;
    if (b < 2056){
        const long t = (long)b * 256 + threadIdx.x;
        const f32x4 z = {0.f, 0.f, 0.f, 0.f};
        if (t < 524288) ((f32x4*)g)[t] = z;
        else            ((f32x4*)cnt)[t - 524288] = z;
    } else {
        int t = (b - 2056) * 256 + threadIdx.x;    // 0..6143
        int i   = t >> 11;
        int rem = t & 2047;
        int ks  = rem >> 9;
        int f   = (rem >> 6) & 7;
        int l   = rem & 63;
        int c   = f * 16 + (l & 15);
        int kb  = ks * 32 + (l >> 4) * 8;
        short8 v;
        #pragma unroll
        for (int j = 0; j < 8; j++)
            v[j] = (short)f2bf(Wfc[i * 16384 + (kb + j) * 128 + c]);
        *(short8*)(Wt + (long)t * 8) = v;
    }
}

// ---------------------------------------------------------------------------
// conv0: h0 (fp32, coalesced) -> hfrag (bf16 frag layout) + segsum + cnt.
// Order: A1 loads+LDS -> sync -> B frag stores (drain during A2) -> A2 segsum.
// ---------------------------------------------------------------------------
__global__ __launch_bounds__(256) void conv0_kernel(const float* __restrict__ h0,
                                                    const int* __restrict__ idx,
                                                    ushort_t* __restrict__ hfrag,
                                                    float* __restrict__ gsum,
                                                    float* __restrict__ cnt)
{
    __shared__ int sidx[128];
    __shared__ __align__(16) char fb[128 * 272];   // 34816 B
    const int tid = threadIdx.x;
    const int bid = ((blockIdx.x & 7) << 8) | (blockIdx.x >> 3);   // XCD swizzle
    const long base = (long)bid * 128;
    if (tid < 128) sidx[tid] = idx[base + tid];

    const int cg = tid & 31, ch = tid >> 5;
    const int rloc0 = ch * 16;

    // A1: 16 independent loads -> LDS tile
    f32x4 v[16];
    #pragma unroll
    for (int j = 0; j < 16; j++)
        v[j] = *(const f32x4*)(h0 + (base + rloc0 + j) * 128 + cg * 4);
    #pragma unroll
    for (int j = 0; j < 16; j++){
        uint2 pk;
        pk.x = (uint_t)f2bf(v[j][0]) | ((uint_t)f2bf(v[j][1]) << 16);
        pk.y = (uint_t)f2bf(v[j][2]) | ((uint_t)f2bf(v[j][3]) << 16);
        *(uint2*)(fb + (rloc0 + j) * 272 + cg * 8) = pk;
    }
    __syncthreads();

    // B: contiguous frag stores (issue early, drain during A2)
    {
        const int r15 = tid & 15, grp = (tid >> 4) & 3, ks = tid >> 6;
        f32x4* dst = (f32x4*)hfrag + (long)bid * 2048 + tid;
        const char* srcrow = fb + ks * 64 + grp * 16;
        #pragma unroll
        for (int rg = 0; rg < 8; rg++){
            f32x4 val = *(const f32x4*)(srcrow + (rg * 16 + r15) * 272);
            dst[rg * 256] = val;
        }
    }

    // A2: register segsum (fp32 exact)
    f32x4 acc = {0.f, 0.f, 0.f, 0.f};
    int cur = sidx[rloc0], n = 0;
    #pragma unroll
    for (int j = 0; j < 16; j++){
        const int g = sidx[rloc0 + j];
        if (g != cur){
            float* gp = gsum + (long)cur * 128 + cg * 4;
            atomicAdd(gp + 0, acc[0]); atomicAdd(gp + 1, acc[1]);
            atomicAdd(gp + 2, acc[2]); atomicAdd(gp + 3, acc[3]);
            if (cg == 0) atomicAdd(cnt + cur, (float)n);
            acc = {0.f, 0.f, 0.f, 0.f}; n = 0; cur = g;
        }
        acc += v[j]; n++;
    }
    float* gp = gsum + (long)cur * 128 + cg * 4;
    atomicAdd(gp + 0, acc[0]); atomicAdd(gp + 1, acc[1]);
    atomicAdd(gp + 2, acc[2]); atomicAdd(gp + 3, acc[3]);
    if (cg == 0) atomicAdd(cnt + cur, (float)n);
}

// ---------------------------------------------------------------------------
// x2 = (g/cnt) @ W_sum + b_sum + b_fc ; re-zeroes g after staging.
// ---------------------------------------------------------------------------
__global__ __launch_bounds__(256) void x2_kernel(float* g,
                                                 const float* __restrict__ cnt,
                                                 const float* __restrict__ Wsum,
                                                 const float* __restrict__ bsum,
                                                 const float* __restrict__ bfc,
                                                 float* __restrict__ x2)
{
    __shared__ float gm[16][128];
    __shared__ float invc[16];
    const int tid = threadIdx.x;
    const int r0 = blockIdx.x * 16;
    if (tid < 16) invc[tid] = 1.f / fmaxf(cnt[r0 + tid], 1.f);
    __syncthreads();
    #pragma unroll
    for (int p = 0; p < 8; p++){
        int e = tid + p * 256;
        int row = e >> 7, col = e & 127;
        float val = g[(long)(r0 + row) * 128 + col];
        gm[row][col] = val * invc[row];
        g[(long)(r0 + row) * 128 + col] = 0.f;      // ready for reuse
    }
    __syncthreads();
    const int c = tid & 127, rh = tid >> 7;
    float acc[8];
    #pragma unroll
    for (int i = 0; i < 8; i++) acc[i] = bsum[c] + bfc[c];
    for (int k = 0; k < 128; k++){
        float w = Wsum[k * 128 + c];
        #pragma unroll
        for (int i = 0; i < 8; i++) acc[i] += gm[rh * 8 + i][k] * w;
    }
    #pragma unroll
    for (int i = 0; i < 8; i++) x2[(long)(r0 + rh * 8 + i) * 128 + c] = acc[i];
}

// ---------------------------------------------------------------------------
// Main layer (R9 structure): b8 loads issued FIRST, single barrier, setprio'd
// MFMA K-loop, batched x2 gather via direct idx reads, fused segsum -> gnext.
// NOWRITE=1 (layer 2): skip dead hout stores.
// ---------------------------------------------------------------------------
template<int NOWRITE>
__global__ __launch_bounds__(256, 4) void layer_kernel(ushort_t* hbuf,
                                                    const ushort_t* __restrict__ Wt,
                                                    const float* __restrict__ x2,
                                                    const int* __restrict__ idx,
                                                    float* __restrict__ gnext)
{
    __shared__ __align__(16) ushort_t seg[128 * 132];
    __shared__ int sidx[128];
    const int tid = threadIdx.x;
    const int bid = ((blockIdx.x & 7) << 8) | (blockIdx.x >> 3);   // XCD swizzle
    const long base = (long)bid * 128;

    const int wv = tid >> 6, ln = tid & 63;
    const int ln15 = ln & 15, grp = ln >> 4;
    const long Rbase = (long)bid * 8 + wv * 2;          // 16-row group index

    // B-fragment loads issued first (the HBM/L3-heavy part, no dependencies)
    short8 b8[8];
    #pragma unroll
    for (int ks = 0; ks < 4; ks++)
        #pragma unroll
        for (int q = 0; q < 2; q++)
            b8[ks * 2 + q] = *(const short8*)(hbuf + (((Rbase + q) * 4 + ks) * 64 + ln) * 8);

    // stage sidx for phase 2 (consumed after the barrier below)
    if (tid < 128) sidx[tid] = idx[base + tid];

    f32x4 acc[2][8];
    #pragma unroll
    for (int q = 0; q < 2; q++)
        #pragma unroll
        for (int f = 0; f < 8; f++) acc[q][f] = {0.f, 0.f, 0.f, 0.f};

    __builtin_amdgcn_s_setprio(1);
    #pragma unroll
    for (int ks = 0; ks < 4; ks++){
        short8 a0[4], a1[4];
        #pragma unroll
        for (int f = 0; f < 4; f++)
            a0[f] = *(const short8*)(Wt + ((long)(ks * 8 + f) * 64 + ln) * 8);
        #pragma unroll
        for (int f = 0; f < 4; f++)
            #pragma unroll
            for (int q = 0; q < 2; q++)
                acc[q][f] = __builtin_amdgcn_mfma_f32_16x16x32_bf16(a0[f], b8[ks * 2 + q], acc[q][f], 0, 0, 0);
        #pragma unroll
        for (int f = 0; f < 4; f++)
            a1[f] = *(const short8*)(Wt + ((long)(ks * 8 + 4 + f) * 64 + ln) * 8);
        #pragma unroll
        for (int f = 0; f < 4; f++)
            #pragma unroll
            for (int q = 0; q < 2; q++)
                acc[q][4 + f] = __builtin_amdgcn_mfma_f32_16x16x32_bf16(a1[f], b8[ks * 2 + q], acc[q][4 + f], 0, 0, 0);
    }
    __builtin_amdgcn_s_setprio(0);

    // epilogue: direct idx read (no barrier dependency), batched x2 gather
    #pragma unroll
    for (int q = 0; q < 2; q++){
        const int lr = wv * 32 + q * 16 + ln15;          // local row 0..127
        const int g = idx[base + lr];
        const float* x2r = x2 + (long)g * 128;
        f32x4 xv[8];
        #pragma unroll
        for (int f = 0; f < 8; f++)
            xv[f] = *(const f32x4*)(x2r + f * 16 + grp * 4);
        #pragma unroll
        for (int f = 0; f < 8; f++){
            const int cb = f * 16 + grp * 4;
            ushort_t h4[4];
            #pragma unroll
            for (int i = 0; i < 4; i++){
                float v = acc[q][f][i] + xv[f][i];
                v = v > 0.f ? v : (__expf(v) - 1.f);
                h4[i] = f2bf(v);
            }
            uint2 pk;
            pk.x = (uint_t)h4[0] | ((uint_t)h4[1] << 16);
            pk.y = (uint_t)h4[2] | ((uint_t)h4[3] << 16);
            if (!NOWRITE){
                const long c16 = ((Rbase + q) * 4 + (f >> 1)) * 64
                               + (2 * (f & 1) + (grp >> 1)) * 16 + ln15;
                *(uint2*)((char*)hbuf + c16 * 16 + (grp & 1) * 8) = pk;
            }
            *(uint2*)((char*)seg + lr * 264 + cb * 2) = pk;
        }
    }
    __syncthreads();

    // phase 2: segment sum of this block's 128 output rows -> gnext
    const int c = tid & 63, ch2 = tid >> 6;              // col pair, row chunk
    const int rr0 = ch2 * 32;
    float a0 = 0.f, a1 = 0.f;
    int cur = sidx[rr0];
    for (int j = 0; j < 32; j++){
        const int rr = rr0 + j;
        const int g = sidx[rr];
        if (g != cur){
            atomicAdd(gnext + (long)cur * 128 + 2 * c,     a0);
            atomicAdd(gnext + (long)cur * 128 + 2 * c + 1, a1);
            a0 = a1 = 0.f; cur = g;
        }
        uint_t u = *(const uint_t*)((const char*)seg + rr * 264 + c * 4);
        a0 += bf2f((ushort_t)(u & 0xffff));
        a1 += bf2f((ushort_t)(u >> 16));
    }
    atomicAdd(gnext + (long)cur * 128 + 2 * c,     a0);
    atomicAdd(gnext + (long)cur * 128 + 2 * c + 1, a1);
}

// ---------------------------------------------------------------------------
// head: out = relu((g/cnt) @ W_f1 + b_f1) @ W_f2 + b_f2
// ---------------------------------------------------------------------------
__global__ __launch_bounds__(256) void head_kernel(const float* __restrict__ g,
                                                   const float* __restrict__ cnt,
                                                   const float* __restrict__ Wf1,
                                                   const float* __restrict__ bf1,
                                                   const float* __restrict__ Wf2,
                                                   const float* __restrict__ bf2,
                                                   float* __restrict__ out)
{
    __shared__ float hm[8][128];
    __shared__ float t1[8][256];
    __shared__ float invc[8];
    const int tid = threadIdx.x;
    const int r0 = blockIdx.x * 8;
    if (tid < 8) invc[tid] = 1.f / fmaxf(cnt[r0 + tid], 1.f);
    __syncthreads();
    #pragma unroll
    for (int p = 0; p < 4; p++){
        int e = tid + p * 256;
        int row = e >> 7, col = e & 127;
        hm[row][col] = g[(long)(r0 + row) * 128 + col] * invc[row];
    }
    __syncthreads();
    {
        const int c = tid;
        float acc[8];
        #pragma unroll
        for (int r = 0; r < 8; r++) acc[r] = bf1[c];
        for (int k = 0; k < 128; k++){
            float w = Wf1[k * 256 + c];
            #pragma unroll
            for (int r = 0; r < 8; r++) acc[r] += hm[r][k] * w;
        }
        #pragma unroll
        for (int r = 0; r < 8; r++) t1[r][c] = fmaxf(acc[r], 0.f);
    }
    __syncthreads();
    if (tid < 80){
        const int r = tid / 10, c = tid % 10;
        float acc = bf2[c];
        for (int k = 0; k < 256; k++) acc += t1[r][k] * Wf2[k * 10 + c];
        out[(long)(r0 + r) * 10 + c] = acc;
    }
}

// ---------------------------------------------------------------------------
extern "C" void kernel_launch(void* const* d_in, const int* in_sizes, int n_in,
                              void* d_out, int out_size, void* d_ws, size_t ws_size,
                              hipStream_t stream)
{
    const float* h0   = (const float*)d_in[0];
    const int*   idx  = (const int*)d_in[1];
    const float* Wfc  = (const float*)d_in[2];
    const float* bfc  = (const float*)d_in[3];
    const float* Wsum = (const float*)d_in[4];
    const float* bsum = (const float*)d_in[5];
    const float* Wf1  = (const float*)d_in[6];
    const float* bf1  = (const float*)d_in[7];
    const float* Wf2  = (const float*)d_in[8];
    const float* bf2  = (const float*)d_in[9];
    float* out = (float*)d_out;

    char* ws = (char*)d_ws;
    ushort_t* hbuf = (ushort_t*)ws;                 // 64 MB (frag layout)
    float* g0  = (float*)(ws + 67108864);           // 4 MB
    float* g1  = (float*)(ws + 71303168);           // 4 MB (contiguous w/ g0)
    float* x2  = (float*)(ws + 75497472);           // 4 MB
    float* cnt = (float*)(ws + 79691776);           // 32 KB
    ushort_t* Wt = (ushort_t*)(ws + 79724544);      // 96 KB (frag layout)
    if (ws_size < 79822848ull) return;              // fail loudly (poisoned out)

    // zero g0||g1 + cnt, and weight prep, in one kernel
    prep_kernel<<<2080, 256, 0, stream>>>(Wfc, Wt, g0, cnt);

    // layer 0: conv0 fuses h0->frag conversion + segsum + cnt  -> g0
    conv0_kernel<<<NSUB / 128, 256, 0, stream>>>(h0, idx, hbuf, g0, cnt);
    x2_kernel<<<NG / 16, 256, 0, stream>>>(g0, cnt, Wsum, bsum, bfc, x2);
    layer_kernel<0><<<NSUB / 128, 256, 0, stream>>>(hbuf, Wt, x2, idx, g1);

    // layer 1 (g1 from layer0 phase-2; g0 was re-zeroed by x2_0)
    x2_kernel<<<NG / 16, 256, 0, stream>>>(g1, cnt, Wsum + 16384, bsum + 128, bfc + 128, x2);
    layer_kernel<0><<<NSUB / 128, 256, 0, stream>>>(hbuf, Wt + 16384, x2, idx, g0);

    // layer 2 (hout never read again -> skip stores)
    x2_kernel<<<NG / 16, 256, 0, stream>>>(g0, cnt, Wsum + 32768, bsum + 256, bfc + 256, x2);
    layer_kernel<1><<<NSUB / 128, 256, 0, stream>>>(hbuf, Wt + 32768, x2, idx, g1);

    // head reads g1 (final segment sums)
    head_kernel<<<NG / 8, 256, 0, stream>>>(g1, cnt, Wf1, bf1, Wf2, bf2, out);
}

// Round 16
// 231.885 us; speedup vs baseline: 5.4372x; 1.0023x over previous
//
#include <hip/hip_runtime.h>

#define NSUB 262144
#define NG   8192
#define DIM  128
#define NT   10

typedef __attribute__((ext_vector_type(4))) float f32x4;
typedef __attribute__((ext_vector_type(8))) short short8;
typedef unsigned short ushort_t;
typedef unsigned int uint_t;

__device__ __forceinline__ float bf2f(ushort_t u){
    union { uint_t i; float f; } v; v.i = ((uint_t)u) << 16; return v.f;
}
__device__ __forceinline__ ushort_t f2bf(float f){
    union { __bf16 b; ushort_t u; } v; v.b = (__bf16)f; return v.u;
}

// ---------------------------------------------------------------------------
// R16 = R15 + sched_barrier(0) in conv0 between A1 loads and pack loop.
// Evidence: R9/R15 conv0 VGPR_Count=56 < 64 needed for v[16] => compiler
// software-pipelined the loads into serial load->pack pairs (~2 in flight).
// Pinning all 16 loads before any pack restores MLP (predict VGPR >= 96).
// Fragment layouts (verified R2/R3):
//  A (Wt):  16B chunk = ((i*4+ks)*8 + f)*64 + lane
//  B (h):   h[row][k] at chunk (R*4 + (k>>5))*64 + ((k>>3)&3)*16 + (row&15),
//           byte (k&7)*2, R = row>>4. 128-row block = contiguous 32KB.
// XCD swizzle (T1, bijective: 2048%8==0).
// ---------------------------------------------------------------------------

// prep: blocks 0..2055 zero g0||g1 (8MB) + cnt; blocks 2056..2079 do W prep.
__global__ __launch_bounds__(256) void prep_kernel(const float* __restrict__ Wfc,
                                                   ushort_t* __restrict__ Wt,
                                                   float* __restrict__ g,
                                                   float* __restrict__ cnt)
{
    const int b = blockIdx.x;
    if (b < 2056){
        const long t = (long)b * 256 + threadIdx.x;
        const f32x4 z = {0.f, 0.f, 0.f, 0.f};
        if (t < 524288) ((f32x4*)g)[t] = z;
        else            ((f32x4*)cnt)[t - 524288] = z;
    } else {
        int t = (b - 2056) * 256 + threadIdx.x;    // 0..6143
        int i   = t >> 11;
        int rem = t & 2047;
        int ks  = rem >> 9;
        int f   = (rem >> 6) & 7;
        int l   = rem & 63;
        int c   = f * 16 + (l & 15);
        int kb  = ks * 32 + (l >> 4) * 8;
        short8 v;
        #pragma unroll
        for (int j = 0; j < 8; j++)
            v[j] = (short)f2bf(Wfc[i * 16384 + (kb + j) * 128 + c]);
        *(short8*)(Wt + (long)t * 8) = v;
    }
}

// ---------------------------------------------------------------------------
// conv0: h0 (fp32, coalesced) -> hfrag (bf16 frag layout) + segsum + cnt.
// A1: 16 loads, ALL pinned in flight via sched_barrier(0); pack -> LDS.
// B:  contiguous frag stores (drain during A2).  A2: register segsum.
// ---------------------------------------------------------------------------
__global__ __launch_bounds__(256) void conv0_kernel(const float* __restrict__ h0,
                                                    const int* __restrict__ idx,
                                                    ushort_t* __restrict__ hfrag,
                                                    float* __restrict__ gsum,
                                                    float* __restrict__ cnt)
{
    __shared__ int sidx[128];
    __shared__ __align__(16) char fb[128 * 272];   // 34816 B
    const int tid = threadIdx.x;
    const int bid = ((blockIdx.x & 7) << 8) | (blockIdx.x >> 3);   // XCD swizzle
    const long base = (long)bid * 128;
    if (tid < 128) sidx[tid] = idx[base + tid];

    const int cg = tid & 31, ch = tid >> 5;
    const int rloc0 = ch * 16;

    // A1: 16 independent loads — keep ALL in flight before any pack
    f32x4 v[16];
    #pragma unroll
    for (int j = 0; j < 16; j++)
        v[j] = *(const f32x4*)(h0 + (base + rloc0 + j) * 128 + cg * 4);
    __builtin_amdgcn_sched_barrier(0);   // pin: no pack hoists above, no load sinks below
    #pragma unroll
    for (int j = 0; j < 16; j++){
        uint2 pk;
        pk.x = (uint_t)f2bf(v[j][0]) | ((uint_t)f2bf(v[j][1]) << 16);
        pk.y = (uint_t)f2bf(v[j][2]) | ((uint_t)f2bf(v[j][3]) << 16);
        *(uint2*)(fb + (rloc0 + j) * 272 + cg * 8) = pk;
    }
    __syncthreads();

    // B: contiguous frag stores (issue early, drain during A2)
    {
        const int r15 = tid & 15, grp = (tid >> 4) & 3, ks = tid >> 6;
        f32x4* dst = (f32x4*)hfrag + (long)bid * 2048 + tid;
        const char* srcrow = fb + ks * 64 + grp * 16;
        #pragma unroll
        for (int rg = 0; rg < 8; rg++){
            f32x4 val = *(const f32x4*)(srcrow + (rg * 16 + r15) * 272);
            dst[rg * 256] = val;
        }
    }

    // A2: register segsum (fp32 exact)
    f32x4 acc = {0.f, 0.f, 0.f, 0.f};
    int cur = sidx[rloc0], n = 0;
    #pragma unroll
    for (int j = 0; j < 16; j++){
        const int g = sidx[rloc0 + j];
        if (g != cur){
            float* gp = gsum + (long)cur * 128 + cg * 4;
            atomicAdd(gp + 0, acc[0]); atomicAdd(gp + 1, acc[1]);
            atomicAdd(gp + 2, acc[2]); atomicAdd(gp + 3, acc[3]);
            if (cg == 0) atomicAdd(cnt + cur, (float)n);
            acc = {0.f, 0.f, 0.f, 0.f}; n = 0; cur = g;
        }
        acc += v[j]; n++;
    }
    float* gp = gsum + (long)cur * 128 + cg * 4;
    atomicAdd(gp + 0, acc[0]); atomicAdd(gp + 1, acc[1]);
    atomicAdd(gp + 2, acc[2]); atomicAdd(gp + 3, acc[3]);
    if (cg == 0) atomicAdd(cnt + cur, (float)n);
}

// ---------------------------------------------------------------------------
// x2 = (g/cnt) @ W_sum + b_sum + b_fc ; re-zeroes g after staging.
// ---------------------------------------------------------------------------
__global__ __launch_bounds__(256) void x2_kernel(float* g,
                                                 const float* __restrict__ cnt,
                                                 const float* __restrict__ Wsum,
                                                 const float* __restrict__ bsum,
                                                 const float* __restrict__ bfc,
                                                 float* __restrict__ x2)
{
    __shared__ float gm[16][128];
    __shared__ float invc[16];
    const int tid = threadIdx.x;
    const int r0 = blockIdx.x * 16;
    if (tid < 16) invc[tid] = 1.f / fmaxf(cnt[r0 + tid], 1.f);
    __syncthreads();
    #pragma unroll
    for (int p = 0; p < 8; p++){
        int e = tid + p * 256;
        int row = e >> 7, col = e & 127;
        float val = g[(long)(r0 + row) * 128 + col];
        gm[row][col] = val * invc[row];
        g[(long)(r0 + row) * 128 + col] = 0.f;      // ready for reuse
    }
    __syncthreads();
    const int c = tid & 127, rh = tid >> 7;
    float acc[8];
    #pragma unroll
    for (int i = 0; i < 8; i++) acc[i] = bsum[c] + bfc[c];
    for (int k = 0; k < 128; k++){
        float w = Wsum[k * 128 + c];
        #pragma unroll
        for (int i = 0; i < 8; i++) acc[i] += gm[rh * 8 + i][k] * w;
    }
    #pragma unroll
    for (int i = 0; i < 8; i++) x2[(long)(r0 + rh * 8 + i) * 128 + c] = acc[i];
}

// ---------------------------------------------------------------------------
// Main layer (R9 structure): b8 loads issued FIRST, single barrier, setprio'd
// MFMA K-loop, batched x2 gather via direct idx reads, fused segsum -> gnext.
// NOWRITE=1 (layer 2): skip dead hout stores.
// ---------------------------------------------------------------------------
template<int NOWRITE>
__global__ __launch_bounds__(256, 4) void layer_kernel(ushort_t* hbuf,
                                                    const ushort_t* __restrict__ Wt,
                                                    const float* __restrict__ x2,
                                                    const int* __restrict__ idx,
                                                    float* __restrict__ gnext)
{
    __shared__ __align__(16) ushort_t seg[128 * 132];
    __shared__ int sidx[128];
    const int tid = threadIdx.x;
    const int bid = ((blockIdx.x & 7) << 8) | (blockIdx.x >> 3);   // XCD swizzle
    const long base = (long)bid * 128;

    const int wv = tid >> 6, ln = tid & 63;
    const int ln15 = ln & 15, grp = ln >> 4;
    const long Rbase = (long)bid * 8 + wv * 2;          // 16-row group index

    // B-fragment loads issued first (the HBM/L3-heavy part, no dependencies)
    short8 b8[8];
    #pragma unroll
    for (int ks = 0; ks < 4; ks++)
        #pragma unroll
        for (int q = 0; q < 2; q++)
            b8[ks * 2 + q] = *(const short8*)(hbuf + (((Rbase + q) * 4 + ks) * 64 + ln) * 8);

    // stage sidx for phase 2 (consumed after the barrier below)
    if (tid < 128) sidx[tid] = idx[base + tid];

    f32x4 acc[2][8];
    #pragma unroll
    for (int q = 0; q < 2; q++)
        #pragma unroll
        for (int f = 0; f < 8; f++) acc[q][f] = {0.f, 0.f, 0.f, 0.f};

    __builtin_amdgcn_s_setprio(1);
    #pragma unroll
    for (int ks = 0; ks < 4; ks++){
        short8 a0[4], a1[4];
        #pragma unroll
        for (int f = 0; f < 4; f++)
            a0[f] = *(const short8*)(Wt + ((long)(ks * 8 + f) * 64 + ln) * 8);
        #pragma unroll
        for (int f = 0; f < 4; f++)
            #pragma unroll
            for (int q = 0; q < 2; q++)
                acc[q][f] = __builtin_amdgcn_mfma_f32_16x16x32_bf16(a0[f], b8[ks * 2 + q], acc[q][f], 0, 0, 0);
        #pragma unroll
        for (int f = 0; f < 4; f++)
            a1[f] = *(const short8*)(Wt + ((long)(ks * 8 + 4 + f) * 64 + ln) * 8);
        #pragma unroll
        for (int f = 0; f < 4; f++)
            #pragma unroll
            for (int q = 0; q < 2; q++)
                acc[q][4 + f] = __builtin_amdgcn_mfma_f32_16x16x32_bf16(a1[f], b8[ks * 2 + q], acc[q][4 + f], 0, 0, 0);
    }
    __builtin_amdgcn_s_setprio(0);

    // epilogue: direct idx read (no barrier dependency), batched x2 gather
    #pragma unroll
    for (int q = 0; q < 2; q++){
        const int lr = wv * 32 + q * 16 + ln15;          // local row 0..127
        const int g = idx[base + lr];
        const float* x2r = x2 + (long)g * 128;
        f32x4 xv[8];
        #pragma unroll
        for (int f = 0; f < 8; f++)
            xv[f] = *(const f32x4*)(x2r + f * 16 + grp * 4);
        #pragma unroll
        for (int f = 0; f < 8; f++){
            const int cb = f * 16 + grp * 4;
            ushort_t h4[4];
            #pragma unroll
            for (int i = 0; i < 4; i++){
                float v = acc[q][f][i] + xv[f][i];
                v = v > 0.f ? v : (__expf(v) - 1.f);
                h4[i] = f2bf(v);
            }
            uint2 pk;
            pk.x = (uint_t)h4[0] | ((uint_t)h4[1] << 16);
            pk.y = (uint_t)h4[2] | ((uint_t)h4[3] << 16);
            if (!NOWRITE){
                const long c16 = ((Rbase + q) * 4 + (f >> 1)) * 64
                               + (2 * (f & 1) + (grp >> 1)) * 16 + ln15;
                *(uint2*)((char*)hbuf + c16 * 16 + (grp & 1) * 8) = pk;
            }
            *(uint2*)((char*)seg + lr * 264 + cb * 2) = pk;
        }
    }
    __syncthreads();

    // phase 2: segment sum of this block's 128 output rows -> gnext
    const int c = tid & 63, ch2 = tid >> 6;              // col pair, row chunk
    const int rr0 = ch2 * 32;
    float a0 = 0.f, a1 = 0.f;
    int cur = sidx[rr0];
    for (int j = 0; j < 32; j++){
        const int rr = rr0 + j;
        const int g = sidx[rr];
        if (g != cur){
            atomicAdd(gnext + (long)cur * 128 + 2 * c,     a0);
            atomicAdd(gnext + (long)cur * 128 + 2 * c + 1, a1);
            a0 = a1 = 0.f; cur = g;
        }
        uint_t u = *(const uint_t*)((const char*)seg + rr * 264 + c * 4);
        a0 += bf2f((ushort_t)(u & 0xffff));
        a1 += bf2f((ushort_t)(u >> 16));
    }
    atomicAdd(gnext + (long)cur * 128 + 2 * c,     a0);
    atomicAdd(gnext + (long)cur * 128 + 2 * c + 1, a1);
}

// ---------------------------------------------------------------------------
// head: out = relu((g/cnt) @ W_f1 + b_f1) @ W_f2 + b_f2
// ---------------------------------------------------------------------------
__global__ __launch_bounds__(256) void head_kernel(const float* __restrict__ g,
                                                   const float* __restrict__ cnt,
                                                   const float* __restrict__ Wf1,
                                                   const float* __restrict__ bf1,
                                                   const float* __restrict__ Wf2,
                                                   const float* __restrict__ bf2,
                                                   float* __restrict__ out)
{
    __shared__ float hm[8][128];
    __shared__ float t1[8][256];
    __shared__ float invc[8];
    const int tid = threadIdx.x;
    const int r0 = blockIdx.x * 8;
    if (tid < 8) invc[tid] = 1.f / fmaxf(cnt[r0 + tid], 1.f);
    __syncthreads();
    #pragma unroll
    for (int p = 0; p < 4; p++){
        int e = tid + p * 256;
        int row = e >> 7, col = e & 127;
        hm[row][col] = g[(long)(r0 + row) * 128 + col] * invc[row];
    }
    __syncthreads();
    {
        const int c = tid;
        float acc[8];
        #pragma unroll
        for (int r = 0; r < 8; r++) acc[r] = bf1[c];
        for (int k = 0; k < 128; k++){
            float w = Wf1[k * 256 + c];
            #pragma unroll
            for (int r = 0; r < 8; r++) acc[r] += hm[r][k] * w;
        }
        #pragma unroll
        for (int r = 0; r < 8; r++) t1[r][c] = fmaxf(acc[r], 0.f);
    }
    __syncthreads();
    if (tid < 80){
        const int r = tid / 10, c = tid % 10;
        float acc = bf2[c];
        for (int k = 0; k < 256; k++) acc += t1[r][k] * Wf2[k * 10 + c];
        out[(long)(r0 + r) * 10 + c] = acc;
    }
}

// ---------------------------------------------------------------------------
extern "C" void kernel_launch(void* const* d_in, const int* in_sizes, int n_in,
                              void* d_out, int out_size, void* d_ws, size_t ws_size,
                              hipStream_t stream)
{
    const float* h0   = (const float*)d_in[0];
    const int*   idx  = (const int*)d_in[1];
    const float* Wfc  = (const float*)d_in[2];
    const float* bfc  = (const float*)d_in[3];
    const float* Wsum = (const float*)d_in[4];
    const float* bsum = (const float*)d_in[5];
    const float* Wf1  = (const float*)d_in[6];
    const float* bf1  = (const float*)d_in[7];
    const float* Wf2  = (const float*)d_in[8];
    const float* bf2  = (const float*)d_in[9];
    float* out = (float*)d_out;

    char* ws = (char*)d_ws;
    ushort_t* hbuf = (ushort_t*)ws;                 // 64 MB (frag layout)
    float* g0  = (float*)(ws + 67108864);           // 4 MB
    float* g1  = (float*)(ws + 71303168);           // 4 MB (contiguous w/ g0)
    float* x2  = (float*)(ws + 75497472);           // 4 MB
    float* cnt = (float*)(ws + 79691776);           // 32 KB
    ushort_t* Wt = (ushort_t*)(ws + 79724544);      // 96 KB (frag layout)
    if (ws_size < 79822848ull) return;              // fail loudly (poisoned out)

    // zero g0||g1 + cnt, and weight prep, in one kernel
    prep_kernel<<<2080, 256, 0, stream>>>(Wfc, Wt, g0, cnt);

    // layer 0: conv0 fuses h0->frag conversion + segsum + cnt  -> g0
    conv0_kernel<<<NSUB / 128, 256, 0, stream>>>(h0, idx, hbuf, g0, cnt);
    x2_kernel<<<NG / 16, 256, 0, stream>>>(g0, cnt, Wsum, bsum, bfc, x2);
    layer_kernel<0><<<NSUB / 128, 256, 0, stream>>>(hbuf, Wt, x2, idx, g1);

    // layer 1 (g1 from layer0 phase-2; g0 was re-zeroed by x2_0)
    x2_kernel<<<NG / 16, 256, 0, stream>>>(g1, cnt, Wsum + 16384, bsum + 128, bfc + 128, x2);
    layer_kernel<0><<<NSUB / 128, 256, 0, stream>>>(hbuf, Wt + 16384, x2, idx, g0);

    // layer 2 (hout never read again -> skip stores)
    x2_kernel<<<NG / 16, 256, 0, stream>>>(g0, cnt, Wsum + 32768, bsum + 256, bfc + 256, x2);
    layer_kernel<1><<<NSUB / 128, 256, 0, stream>>>(hbuf, Wt + 32768, x2, idx, g1);

    // head reads g1 (final segment sums)
    head_kernel<<<NG / 8, 256, 0, stream>>>(g1, cnt, Wf1, bf1, Wf2, bf2, out);
}